// Round 10
// baseline (220.352 us; speedup 1.0000x reference)
//
#include <hip/hip_runtime.h>
#include <math.h>

#define Mv 8
#define Nv 8192
#define Kv 256
#define BPM 128           // slabs per m -> 1024 blocks total, 4 per CU
#define NBLK (Mv*BPM)
#define NPB (Nv/BPM)      // 64 points per block
#define NITER 6
#define EPSILON_C 0.01f
#define GAMMA_C 0.005f

// LDS row swizzles: quad lanes read distinct banks; whole-wave reads broadcast
#define SWZK(k) ((((k)&63)<<2)|((k)>>6))   // k = ks*64+j  -> row (j<<2)|ks
#define SWZP(p) ((((p)&15)<<2)|((p)>>4))   // p = ns*16+j  -> row (j<<2)|ns

// ws layout: 3 x (2-replica) acc buffers (buffer 0 memset by host)
#define AC_STATS 0        // 128 (M x 16)
#define AC_L     128      // 2048 (M x K)
#define AC_W     2176     // 6144 (M x 3 x K)
#define AC_H     8320     // 2048 (M x K)
#define ACCSZ    10368
#define BUFSZ    (2*ACCSZ)    // 2 replicas: atomic RMW depth stays 64

// sum over the 2 replicas (plain cached loads -- kernel boundary = coherence)
#define ALD2(accp, off) ((accp)[off] + (accp)[(off)+ACCSZ])

// ---- wave-wide sum via DPP; wave-uniform result. All lanes must be active.
__device__ __forceinline__ float wave_red_sum(float x) {
  int v;
  float t;
  v = __builtin_bit_cast(int, x);
  t = __builtin_bit_cast(float, __builtin_amdgcn_update_dpp(0, v, 0x111, 0xf, 0xf, true));  // row_shr:1
  x += t; v = __builtin_bit_cast(int, x);
  t = __builtin_bit_cast(float, __builtin_amdgcn_update_dpp(0, v, 0x112, 0xf, 0xf, true));  // row_shr:2
  x += t; v = __builtin_bit_cast(int, x);
  t = __builtin_bit_cast(float, __builtin_amdgcn_update_dpp(0, v, 0x114, 0xf, 0xf, true));  // row_shr:4
  x += t; v = __builtin_bit_cast(int, x);
  t = __builtin_bit_cast(float, __builtin_amdgcn_update_dpp(0, v, 0x118, 0xf, 0xf, true));  // row_shr:8
  x += t; v = __builtin_bit_cast(int, x);
  t = __builtin_bit_cast(float, __builtin_amdgcn_update_dpp(0, v, 0x142, 0xa, 0xf, false)); // row_bcast:15
  x += t; v = __builtin_bit_cast(int, x);
  t = __builtin_bit_cast(float, __builtin_amdgcn_update_dpp(0, v, 0x143, 0xc, 0xf, false)); // row_bcast:31
  x += t;
  return __builtin_bit_cast(float, __builtin_amdgcn_readlane(__builtin_bit_cast(int, x), 63));
}

// ---- sum across a quad of lanes (xor1 + xor2 via quad_perm DPP). All lanes get it.
__device__ __forceinline__ float quad_red_sum(float x) {
  int v = __builtin_bit_cast(int, x);
  float t = __builtin_bit_cast(float, __builtin_amdgcn_update_dpp(0, v, 0xB1, 0xf, 0xf, true)); // quad_perm[1,0,3,2]
  x += t; v = __builtin_bit_cast(int, x);
  t = __builtin_bit_cast(float, __builtin_amdgcn_update_dpp(0, v, 0x4E, 0xf, 0xf, true));       // quad_perm[2,3,0,1]
  x += t;
  return x;
}

__device__ __forceinline__ float sel4(int c, float a0, float a1, float a2, float a3) {
  float r = a0;
  r = (c==1) ? a1 : r;
  r = (c==2) ? a2 : r;
  r = (c==3) ? a3 : r;
  return r;
}

// ---- fp32 Jacobi rotation, COMPILE-TIME pair, named scalars only.
#define JROTF(app,aqq,apq,apr,aqr, vp0,vp1,vp2, vq0,vq1,vq2) do {           \
    float tau_ = (aqq - app) * __builtin_amdgcn_rcpf(2.0f*apq);             \
    float tt_ = __builtin_amdgcn_rcpf(fabsf(tau_) +                         \
                   __builtin_amdgcn_sqrtf(fmaf(tau_,tau_,1.0f)));           \
    tt_ = (tau_ < 0.0f) ? -tt_ : tt_;                                       \
    tt_ = (apq == 0.0f) ? 0.0f : tt_;                                       \
    float c_ = __builtin_amdgcn_rsqf(fmaf(tt_,tt_,1.0f)), s_ = tt_*c_;      \
    float papq_ = apq;                                                      \
    app = fmaf(-tt_,papq_,app); aqq = fmaf(tt_,papq_,aqq); apq = 0.0f;      \
    float tp_ = apr, tq_ = aqr;                                             \
    apr = c_*tp_ - s_*tq_; aqr = s_*tp_ + c_*tq_;                           \
    tp_=vp0; tq_=vq0; vp0=c_*tp_-s_*tq_; vq0=s_*tp_+c_*tq_;                 \
    tp_=vp1; tq_=vq1; vp1=c_*tp_-s_*tq_; vq1=s_*tp_+c_*tq_;                 \
    tp_=vp2; tq_=vq2; vp2=c_*tp_-s_*tq_; vq2=s_*tp_+c_*tq_;                 \
  } while(0)

#define CSWAP3F(la,lb, a0,a1,a2, b0,b1,b2) do {                             \
    if (la < lb) { float t_;                                                \
      t_=la; la=lb; lb=t_; t_=a0; a0=b0; b0=t_;                             \
      t_=a1; a1=b1; b1=t_; t_=a2; a2=b2; b2=t_; }                           \
  } while(0)

// ---- redundant small update for iteration `itprev` from 2-replica acc.
// Runs identically in every block. Contains one internal __syncthreads;
// caller must __syncthreads() after before reading other threads' sX/sQ.
template<int ITPREV>
__device__ __forceinline__ void small_update(const float* __restrict__ acc,
                                             const float* __restrict__ X0,
                                             int tid,
                                             float (*sX)[3], float* sQ,
                                             float (*sR)[9], float (*sT)[3],
                                             float* sTn) {
  const int k = tid;
  float lk[Mv], w0v[Mv], w1v[Mv], w2v[Mv], hk[Mv];
  #pragma unroll
  for (int mm=0;mm<Mv;mm++) {
    lk[mm]  = ALD2(acc, AC_L + mm*Kv + k);
    w0v[mm] = ALD2(acc, AC_W + (mm*3+0)*Kv + k);
    w1v[mm] = ALD2(acc, AC_W + (mm*3+1)*Kv + k);
    w2v[mm] = ALD2(acc, AC_W + (mm*3+2)*Kv + k);
    hk[mm]  = ALD2(acc, AC_H + mm*Kv + k);
  }
  float xp0 = 0.f, xp1 = 0.f, xp2 = 0.f;
  if (ITPREV <= 1) {
    xp0 = X0[k*3+0]; xp1 = X0[k*3+1]; xp2 = X0[k*3+2];
  }

  if (tid < Mv) {
    int mm = tid;
    const int sb = AC_STATS + mm*16;
    float s0=ALD2(acc,sb+0), s1=ALD2(acc,sb+1), s2v=ALD2(acc,sb+2),
          s3=ALD2(acc,sb+3), s4=ALD2(acc,sb+4), s5=ALD2(acc,sb+5),
          s6=ALD2(acc,sb+6), s7=ALD2(acc,sb+7), s8=ALD2(acc,sb+8),
          s9=ALD2(acc,sb+9), s10=ALD2(acc,sb+10), s11=ALD2(acc,sb+11),
          s12=ALD2(acc,sb+12), s13=ALD2(acc,sb+13), s14=ALD2(acc,sb+14),
          s15=ALD2(acc,sb+15);
    float z = s0;
    float mX0 = s1, mX1 = s2v, mX2 = s3;
    float mW0 = s4, mW1 = s5, mW2 = s6;
    float iz = __builtin_amdgcn_rcpf(z);
    float P00 = s7  - mX0*mW0*iz;
    float P01 = s8  - mX0*mW1*iz;
    float P02 = s9  - mX0*mW2*iz;
    float P10 = s10 - mX1*mW0*iz;
    float P11 = s11 - mX1*mW1*iz;
    float P12 = s12 - mX1*mW2*iz;
    float P20 = s13 - mX2*mW0*iz;
    float P21 = s14 - mX2*mW1*iz;
    float P22 = s15 - mX2*mW2*iz;
    float a00 = P00*P00 + P10*P10 + P20*P20;
    float a01 = P00*P01 + P10*P11 + P20*P21;
    float a02 = P00*P02 + P10*P12 + P20*P22;
    float a11 = P01*P01 + P11*P11 + P21*P21;
    float a12 = P01*P02 + P11*P12 + P21*P22;
    float a22 = P02*P02 + P12*P12 + P22*P22;
    float v00=1, v01=0, v02=0, v10=0, v11=1, v12=0, v20=0, v21=0, v22=1;
    #pragma unroll 1
    for (int sweep = 0; sweep < 5; sweep++) {
      JROTF(a00,a11,a01, a02,a12, v00,v10,v20, v01,v11,v21);
      JROTF(a00,a22,a02, a01,a12, v00,v10,v20, v02,v12,v22);
      JROTF(a11,a22,a12, a01,a02, v01,v11,v21, v02,v12,v22);
    }
    float l0 = a00, l1 = a11, l2 = a22;
    CSWAP3F(l0,l1, v00,v10,v20, v01,v11,v21);
    CSWAP3F(l1,l2, v01,v11,v21, v02,v12,v22);
    CSWAP3F(l0,l1, v00,v10,v20, v01,v11,v21);
    float detP = P00*(P11*P22-P12*P21) - P01*(P10*P22-P12*P20)
               + P02*(P10*P21-P11*P20);
    float s2d = (detP < 0.0f) ? -1.0f : 1.0f;
    float tiny = 1e-18f*l0 + 1e-30f;
    float w0i = __builtin_amdgcn_rsqf(fmaxf(l0,tiny));
    float w1i = __builtin_amdgcn_rsqf(fmaxf(l1,tiny));
    float w2i = s2d*__builtin_amdgcn_rsqf(fmaxf(l2,tiny));
    float M00 = w0i*v00*v00 + w1i*v01*v01 + w2i*v02*v02;
    float M01 = w0i*v00*v10 + w1i*v01*v11 + w2i*v02*v12;
    float M02 = w0i*v00*v20 + w1i*v01*v21 + w2i*v02*v22;
    float M11 = w0i*v10*v10 + w1i*v11*v11 + w2i*v12*v12;
    float M12 = w0i*v10*v20 + w1i*v11*v21 + w2i*v12*v22;
    float M22 = w0i*v20*v20 + w1i*v21*v21 + w2i*v22*v22;
    float R00n = P00*M00 + P01*M01 + P02*M02;
    float R01n = P00*M01 + P01*M11 + P02*M12;
    float R02n = P00*M02 + P01*M12 + P02*M22;
    float R10n = P10*M00 + P11*M01 + P12*M02;
    float R11n = P10*M01 + P11*M11 + P12*M12;
    float R12n = P10*M02 + P11*M12 + P12*M22;
    float R20n = P20*M00 + P21*M01 + P22*M02;
    float R21n = P20*M01 + P21*M11 + P22*M12;
    float R22n = P20*M02 + P21*M12 + P22*M22;
    float tm0 = (mX0 - (R00n*mW0 + R01n*mW1 + R02n*mW2))*iz;
    float tm1 = (mX1 - (R10n*mW0 + R11n*mW1 + R12n*mW2))*iz;
    float tm2 = (mX2 - (R20n*mW0 + R21n*mW1 + R22n*mW2))*iz;
    sR[mm][0]=R00n; sR[mm][1]=R01n; sR[mm][2]=R02n;
    sR[mm][3]=R10n; sR[mm][4]=R11n; sR[mm][5]=R12n;
    sR[mm][6]=R20n; sR[mm][7]=R21n; sR[mm][8]=R22n;
    sT[mm][0]=tm0; sT[mm][1]=tm1; sT[mm][2]=tm2;
    sTn[mm] = tm0*tm0 + tm1*tm1 + tm2*tm2;
  }
  __syncthreads();
  {
    float den = 0.f, Xn0=0.f, Xn1=0.f, Xn2=0.f, S2=0.f;
    #pragma unroll
    for (int mm=0;mm<Mv;mm++) {
      float r0 = sR[mm][0]*w0v[mm] + sR[mm][1]*w1v[mm] + sR[mm][2]*w2v[mm];
      float r1 = sR[mm][3]*w0v[mm] + sR[mm][4]*w1v[mm] + sR[mm][5]*w2v[mm];
      float r2 = sR[mm][6]*w0v[mm] + sR[mm][7]*w1v[mm] + sR[mm][8]*w2v[mm];
      float tt0 = sT[mm][0], tt1 = sT[mm][1], tt2 = sT[mm][2];
      den += lk[mm];
      Xn0 += r0 + tt0*lk[mm]; Xn1 += r1 + tt1*lk[mm]; Xn2 += r2 + tt2*lk[mm];
      S2  += hk[mm] + 2.f*(tt0*r0+tt1*r1+tt2*r2) + sTn[mm]*lk[mm];
    }
    float x0, x1, x2;
    if (ITPREV > 1) { float inv = __builtin_amdgcn_rcpf(den);
                      x0=Xn0*inv; x1=Xn1*inv; x2=Xn2*inv; }
    else            { x0=xp0; x1=xp1; x2=xp2; }
    float wn = S2 + (x0*x0+x1*x1+x2*x2)*den - 2.f*(x0*Xn0+x1*Xn1+x2*Xn2);
    float qn = 3.f*den / (wn + 3.f*den*EPSILON_C);
    sX[k][0]=x0; sX[k][1]=x1; sX[k][2]=x2;
    sQ[k] = qn;
  }
}

// ------------------------------------------- one-iteration kernel (1024 blocks)
// Register-tiled two-pass; 4 blocks/CU (launch_bounds caps VGPR at 128).
template<int IT>
__global__ __launch_bounds__(256, 4) void p_iter(const float* __restrict__ Vs,
                                                 const float* __restrict__ X0,
                                                 const float* __restrict__ Q0,
                                                 float* __restrict__ ws) {
  __shared__ __align__(16) float sC4[Kv][4];   // {kXx,kXy,kXz,kA} swizzled
  __shared__ float sKC[Kv];                    // kQ32*2^kB swizzled
  __shared__ __align__(16) float sP4[NPB][4];  // {px,py,pz,tvn} swizzled
  __shared__ __align__(16) float sV4[NPB][4];  // {vx,vy,vz,vn} swizzled
  __shared__ float sLi[NPB];                   // -log2(S+beta) swizzled
  __shared__ float st4[4][16];
  __shared__ float sX[Kv][3];
  __shared__ float sQ[Kv];
  __shared__ float sR[Mv][9];
  __shared__ float sT[Mv][3];
  __shared__ float sTn[Mv];
  __shared__ float sredq[4];
  __shared__ float sredt[12];

  int tid  = threadIdx.x;
  int wave = tid >> 6, lane = tid & 63;
  int bid  = blockIdx.x;
  int m    = bid / BPM;
  int blk  = bid % BPM;
  int n0   = blk * NPB;

  float* acc  = ws + (IT % 3)*BUFSZ + (blk & 1)*ACCSZ;  // own replica
  float* accz = ws + ((IT+1) % 3)*BUFSZ;

  // ---- hoisted loads: own point + own q (latency hides under the prologue)
  const float* V0 = Vs + (size_t)(m*3+0)*Nv;
  const float* V1 = Vs + (size_t)(m*3+1)*Nv;
  const float* V2 = Vs + (size_t)(m*3+2)*Nv;
  float vx=0.f, vy=0.f, vz=0.f;
  if (tid < NPB) {
    int n = n0 + tid;
    vx = V0[n]; vy = V1[n]; vz = V2[n];
  }
  float q_own = Q0[tid];
  { float s = wave_red_sum(q_own);
    if (lane == 0) sredq[wave] = s; }

  float t00=0.f, t01=0.f, t02=0.f;
  if (IT == 0) {
    // t0 (redundant per block: mean over ALL Nv points of own m; L2-resident)
    float sx=0.f, sy=0.f, sz=0.f;
    for (int n = tid; n < Nv; n += 256) { sx += V0[n]; sy += V1[n]; sz += V2[n]; }
    sx = wave_red_sum(sx); sy = wave_red_sum(sy); sz = wave_red_sum(sz);
    if (lane == 0) { sredt[wave] = sx; sredt[4+wave] = sy; sredt[8+wave] = sz; }
    sX[tid][0] = X0[3*tid+0];
    sX[tid][1] = X0[3*tid+1];
    sX[tid][2] = X0[3*tid+2];
    sQ[tid]    = q_own;
    __syncthreads();
    t00 = -(sredt[0]+sredt[1]+sredt[2]+sredt[3]) * (1.f/(float)Nv);
    t01 = -(sredt[4]+sredt[5]+sredt[6]+sredt[7]) * (1.f/(float)Nv);
    t02 = -(sredt[8]+sredt[9]+sredt[10]+sredt[11]) * (1.f/(float)Nv);
  } else {
    const float* accp = ws + ((IT+2) % 3)*BUFSZ;  // (IT-1)%3, both replicas
    small_update<(IT > 0) ? (IT-1) : 0>(accp, X0, tid, sX, sQ, sR, sT, sTn);
    __syncthreads();
  }
  float beta;
  { float mq = (sredq[0]+sredq[1]+sredq[2]+sredq[3]) * (1.f/(float)Kv);
    beta = GAMMA_C * mq * sqrtf(mq); }

  // partitioned zero of buffer (IT+1)%3, both replicas (21*1024 >= BUFSZ)
  if (IT < NITER-1) {
    int base = bid*21;
    if (tid < 21 && base + tid < BUFSZ) accz[base + tid] = 0.f;
  }

  // own-m R, t
  float R00,R01,R02,R10,R11,R12,R20,R21,R22, t0,t1,t2;
  if (IT == 0) {
    R00=1;R01=0;R02=0; R10=0;R11=1;R12=0; R20=0;R21=0;R22=1;
    t0=t00; t1=t01; t2=t02;
  } else {
    R00=sR[m][0];R01=sR[m][1];R02=sR[m][2];
    R10=sR[m][3];R11=sR[m][4];R12=sR[m][5];
    R20=sR[m][6];R21=sR[m][7];R22=sR[m][8];
    t0=sT[m][0]; t1=sT[m][1]; t2=sT[m][2];
  }

  // ---- prep: per-k coefficients (k=tid) -> swizzled LDS
  const float L2E = 1.4426950408889634f;
  {
    float xx = sX[tid][0], xy = sX[tid][1], xz = sX[tid][2];
    float q  = sQ[tid];
    float qL = q * L2E;
    float kA = -0.5f*qL;
    float kB = kA*(xx*xx+xy*xy+xz*xz);
    float kQ32 = q*sqrtf(q);
    int rr = SWZK(tid);
    *reinterpret_cast<float4*>(&sC4[rr][0]) = make_float4(qL*xx, qL*xy, qL*xz, kA);
    sKC[rr] = kQ32 * __builtin_amdgcn_exp2f(kB);
  }
  // ---- transform own point (loads already in registers)
  if (tid < NPB) {
    float px = fmaf(R00,vx, fmaf(R01,vy, fmaf(R02,vz, t0)));
    float py = fmaf(R10,vx, fmaf(R11,vy, fmaf(R12,vz, t1)));
    float pz = fmaf(R20,vx, fmaf(R21,vy, fmaf(R22,vz, t2)));
    float tvn = fmaf(px,px, fmaf(py,py, pz*pz));
    float vn  = fmaf(vx,vx, fmaf(vy,vy, vz*vz));
    int pr = SWZP(tid);
    *reinterpret_cast<float4*>(&sP4[pr][0]) = make_float4(px,py,pz,tvn);
    *reinterpret_cast<float4*>(&sV4[pr][0]) = make_float4(vx,vy,vz,vn);
  }
  __syncthreads();

  // ---- pass 1: denominators. thread (pg = tid>>2 = point, ks = tid&3)
  {
    int ks = tid & 3, pg = tid >> 2;          // pg in 0..63 = own point
    float4 P0 = *reinterpret_cast<const float4*>(&sP4[SWZP(pg)][0]);
    float s0 = 0.f;
    #pragma unroll 4
    for (int j = 0; j < Kv/4; j++) {          // k = ks*64 + j
      int row = (j<<2) | ks;
      float4 c4 = *reinterpret_cast<const float4*>(&sC4[row][0]);
      float kc = sKC[row];
      float a0 = fmaf(P0.x,c4.x, fmaf(P0.y,c4.y, fmaf(P0.z,c4.z, P0.w*c4.w)));
      s0 = fmaf(__builtin_amdgcn_exp2f(a0), kc, s0);
    }
    float S0 = quad_red_sum(s0);
    if (ks == 0) sLi[SWZP(pg)] = -__log2f(S0 + beta);
  }
  __syncthreads();

  // ---- pass 2: thread (kg = tid>>2, ns = tid&3); owns k = 4kg..4kg+3
  float cXx0,cXy0,cXz0,cA0,cC0, cXx1,cXy1,cXz1,cA1,cC1,
        cXx2,cXy2,cXz2,cA2,cC2, cXx3,cXy3,cXz3,cA3,cC3;
  {
    int kg = tid >> 2;
    #define LDC(c) { int rr = SWZK(4*kg + c); \
      float4 t4 = *reinterpret_cast<const float4*>(&sC4[rr][0]); \
      cXx##c=t4.x; cXy##c=t4.y; cXz##c=t4.z; cA##c=t4.w; cC##c=sKC[rr]; }
    LDC(0) LDC(1) LDC(2) LDC(3)
    #undef LDC
  }
  float L0=0,L1=0,L2=0,L3=0, Wx0=0,Wx1=0,Wx2=0,Wx3=0,
        Wy0=0,Wy1=0,Wy2=0,Wy3=0, Wz0=0,Wz1=0,Wz2=0,Wz3=0,
        H0=0,H1=0,H2=0,H3=0;
  {
    int ns = tid & 3;
    #pragma unroll 4
    for (int j = 0; j < NPB/4; j++) {         // n = ns*16 + j
      int prow = (j<<2) | ns;
      float4 p4 = *reinterpret_cast<const float4*>(&sP4[prow][0]);
      float4 v4 = *reinterpret_cast<const float4*>(&sV4[prow][0]);
      float li = sLi[prow];
      #define P2K(c) { \
        float arg = fmaf(p4.w, cA##c, li); \
        arg = fmaf(p4.x, cXx##c, fmaf(p4.y, cXy##c, fmaf(p4.z, cXz##c, arg))); \
        float e = __builtin_amdgcn_exp2f(arg) * cC##c; \
        L##c += e; \
        Wx##c = fmaf(e, v4.x, Wx##c); Wy##c = fmaf(e, v4.y, Wy##c); \
        Wz##c = fmaf(e, v4.z, Wz##c); H##c  = fmaf(e, v4.w, H##c); }
      P2K(0) P2K(1) P2K(2) P2K(3)
      #undef P2K
    }
  }
  // quad-reduce the 4 n-quarters; then thread t owns k = t
  L0=quad_red_sum(L0); L1=quad_red_sum(L1); L2=quad_red_sum(L2); L3=quad_red_sum(L3);
  Wx0=quad_red_sum(Wx0); Wx1=quad_red_sum(Wx1); Wx2=quad_red_sum(Wx2); Wx3=quad_red_sum(Wx3);
  Wy0=quad_red_sum(Wy0); Wy1=quad_red_sum(Wy1); Wy2=quad_red_sum(Wy2); Wy3=quad_red_sum(Wy3);
  Wz0=quad_red_sum(Wz0); Wz1=quad_red_sum(Wz1); Wz2=quad_red_sum(Wz2); Wz3=quad_red_sum(Wz3);
  H0=quad_red_sum(H0); H1=quad_red_sum(H1); H2=quad_red_sum(H2); H3=quad_red_sum(H3);
  int c = tid & 3;
  float vL  = sel4(c, L0,L1,L2,L3);
  float vWx = sel4(c, Wx0,Wx1,Wx2,Wx3);
  float vWy = sel4(c, Wy0,Wy1,Wy2,Wy3);
  float vWz = sel4(c, Wz0,Wz1,Wz2,Wz3);
  float vH  = sel4(c, H0,H1,H2,H3);
  atomicAdd(&acc[AC_L + m*Kv + tid], vL);
  atomicAdd(&acc[AC_W + (m*3+0)*Kv + tid], vWx);
  atomicAdd(&acc[AC_W + (m*3+1)*Kv + tid], vWy);
  atomicAdd(&acc[AC_W + (m*3+2)*Kv + tid], vWz);
  atomicAdd(&acc[AC_H + m*Kv + tid], vH);

  // ---- stats epilogue (k = tid)
  {
    float q  = sQ[tid];
    float x0 = sX[tid][0], x1 = sX[tid][1], x2 = sX[tid][2];
    float bk = vL*q;
    float sw0 = vWx*q, sw1 = vWy*q, sw2 = vWz*q;
    float pr[16];
    pr[0]=bk;  pr[1]=bk*x0; pr[2]=bk*x1; pr[3]=bk*x2;
    pr[4]=sw0; pr[5]=sw1;   pr[6]=sw2;
    pr[7]=sw0*x0;  pr[8]=sw1*x0;  pr[9]=sw2*x0;
    pr[10]=sw0*x1; pr[11]=sw1*x1; pr[12]=sw2*x1;
    pr[13]=sw0*x2; pr[14]=sw1*x2; pr[15]=sw2*x2;
    float red[16];
    #pragma unroll
    for (int v2=0; v2<16; v2++) red[v2] = wave_red_sum(pr[v2]);
    if (lane == 0) {
      #pragma unroll
      for (int v2=0; v2<16; v2++) st4[wave][v2] = red[v2];
    }
    __syncthreads();
    if (tid < 16)
      atomicAdd(&acc[AC_STATS + m*16 + ((tid + blk) & 15)],
                st4[0][(tid+blk)&15]+st4[1][(tid+blk)&15]+
                st4[2][(tid+blk)&15]+st4[3][(tid+blk)&15]);
  }
}

// ------------------------------- final: prologue finalizes iter 5, then write
#define OUT_TOTAL (Mv*3*Nv + 72 + 24 + Kv*3)
__global__ __launch_bounds__(256) void p3_final(const float* __restrict__ Vs,
                                                const float* __restrict__ X0,
                                                const float* __restrict__ ws,
                                                float* __restrict__ out) {
  __shared__ float sX[Kv][3];
  __shared__ float sQ[Kv];
  __shared__ float sR[Mv][9];
  __shared__ float sT[Mv][3];
  __shared__ float sTn[Mv];
  int tid = threadIdx.x;
  const float* acc = ws + ((NITER-1) % 3)*BUFSZ;
  small_update<NITER-1>(acc, X0, tid, sX, sQ, sR, sT, sTn);
  __syncthreads();

  for (int idx = blockIdx.x*256 + tid; idx < OUT_TOTAL; idx += 256*256) {
    if (idx < Mv*3*Nv) {
      int m = idx / (3*Nv);
      int r = idx % (3*Nv);
      int d = r / Nv;
      int n = r % Nv;
      float vx = Vs[(size_t)(m*3+0)*Nv + n];
      float vy = Vs[(size_t)(m*3+1)*Nv + n];
      float vz = Vs[(size_t)(m*3+2)*Nv + n];
      out[idx] = fmaf(sR[m][d*3+0],vx,
                 fmaf(sR[m][d*3+1],vy,
                 fmaf(sR[m][d*3+2],vz, sT[m][d])));
    } else {
      int j = idx - Mv*3*Nv;
      float v;
      if (j < 72)      v = ((float*)sR)[j];
      else if (j < 96) v = ((float*)sT)[j-72];
      else             v = ((float*)sX)[j-96];
      out[idx] = v;
    }
  }
}

extern "C" void kernel_launch(void* const* d_in, const int* in_sizes, int n_in,
                              void* d_out, int out_size, void* d_ws, size_t ws_size,
                              hipStream_t stream) {
  const float* Vs = (const float*)d_in[0];
  const float* X0 = (const float*)d_in[1];
  const float* Q0 = (const float*)d_in[2];
  float* out = (float*)d_out;
  float* ws  = (float*)d_ws;

  // zero acc buffer 0 (both replicas); buffers 1,2 zeroed inside p_iter<0>/<1>
  hipMemsetAsync(ws, 0, BUFSZ * sizeof(float), stream);
  p_iter<0><<<NBLK, 256, 0, stream>>>(Vs, X0, Q0, ws);
  p_iter<1><<<NBLK, 256, 0, stream>>>(Vs, X0, Q0, ws);
  p_iter<2><<<NBLK, 256, 0, stream>>>(Vs, X0, Q0, ws);
  p_iter<3><<<NBLK, 256, 0, stream>>>(Vs, X0, Q0, ws);
  p_iter<4><<<NBLK, 256, 0, stream>>>(Vs, X0, Q0, ws);
  p_iter<5><<<NBLK, 256, 0, stream>>>(Vs, X0, Q0, ws);
  p3_final<<<256, 256, 0, stream>>>(Vs, X0, ws, out);
}

// Round 11
// 175.275 us; speedup vs baseline: 1.2572x; 1.2572x over previous
//
#include <hip/hip_runtime.h>
#include <math.h>

#define Mv 8
#define Nv 8192
#define Kv 256
#define BPM 64            // slabs per m -> 512 blocks total, 2 per CU
#define NBLK (Mv*BPM)
#define NPB (Nv/BPM)      // 128 points per block
#define NITER 6
#define EPSILON_C 0.01f
#define GAMMA_C 0.005f

// LDS row swizzles: 4 distinct rows read per wave land in distinct banks
#define SWZK(k) ((((k)&63)<<2)|((k)>>6))   // k = ks*64+j  -> row (j<<2)|ks
#define SWZP(p) ((((p)&31)<<2)|((p)>>5))   // p = ns*32+j  -> row (j<<2)|ns

// ws layout: 3 x ACCSZ triple-buffered accumulators (buffer 0 memset by host)
#define AC_STATS 0        // 128 (M x 16)
#define AC_L     128      // 2048 (M x K)
#define AC_W     2176     // 6144 (M x 3 x K)
#define AC_H     8320     // 2048 (M x K)
#define ACCSZ    10368

// ---- wave-wide sum via DPP; wave-uniform result. All lanes must be active.
__device__ __forceinline__ float wave_red_sum(float x) {
  int v;
  float t;
  v = __builtin_bit_cast(int, x);
  t = __builtin_bit_cast(float, __builtin_amdgcn_update_dpp(0, v, 0x111, 0xf, 0xf, true));  // row_shr:1
  x += t; v = __builtin_bit_cast(int, x);
  t = __builtin_bit_cast(float, __builtin_amdgcn_update_dpp(0, v, 0x112, 0xf, 0xf, true));  // row_shr:2
  x += t; v = __builtin_bit_cast(int, x);
  t = __builtin_bit_cast(float, __builtin_amdgcn_update_dpp(0, v, 0x114, 0xf, 0xf, true));  // row_shr:4
  x += t; v = __builtin_bit_cast(int, x);
  t = __builtin_bit_cast(float, __builtin_amdgcn_update_dpp(0, v, 0x118, 0xf, 0xf, true));  // row_shr:8
  x += t; v = __builtin_bit_cast(int, x);
  t = __builtin_bit_cast(float, __builtin_amdgcn_update_dpp(0, v, 0x142, 0xa, 0xf, false)); // row_bcast:15
  x += t; v = __builtin_bit_cast(int, x);
  t = __builtin_bit_cast(float, __builtin_amdgcn_update_dpp(0, v, 0x143, 0xc, 0xf, false)); // row_bcast:31
  x += t;
  return __builtin_bit_cast(float, __builtin_amdgcn_readlane(__builtin_bit_cast(int, x), 63));
}

// ---- sum across a quad of lanes (xor1 + xor2 via quad_perm DPP). All lanes get it.
__device__ __forceinline__ float quad_red_sum(float x) {
  int v = __builtin_bit_cast(int, x);
  float t = __builtin_bit_cast(float, __builtin_amdgcn_update_dpp(0, v, 0xB1, 0xf, 0xf, true)); // quad_perm[1,0,3,2]
  x += t; v = __builtin_bit_cast(int, x);
  t = __builtin_bit_cast(float, __builtin_amdgcn_update_dpp(0, v, 0x4E, 0xf, 0xf, true));       // quad_perm[2,3,0,1]
  x += t;
  return x;
}

__device__ __forceinline__ float sel4(int c, float a0, float a1, float a2, float a3) {
  float r = a0;
  r = (c==1) ? a1 : r;
  r = (c==2) ? a2 : r;
  r = (c==3) ? a3 : r;
  return r;
}

// ---- fp32 Jacobi rotation, COMPILE-TIME pair, named scalars only.
#define JROTF(app,aqq,apq,apr,aqr, vp0,vp1,vp2, vq0,vq1,vq2) do {           \
    float tau_ = (aqq - app) * __builtin_amdgcn_rcpf(2.0f*apq);             \
    float tt_ = __builtin_amdgcn_rcpf(fabsf(tau_) +                         \
                   __builtin_amdgcn_sqrtf(fmaf(tau_,tau_,1.0f)));           \
    tt_ = (tau_ < 0.0f) ? -tt_ : tt_;                                       \
    tt_ = (apq == 0.0f) ? 0.0f : tt_;                                       \
    float c_ = __builtin_amdgcn_rsqf(fmaf(tt_,tt_,1.0f)), s_ = tt_*c_;      \
    float papq_ = apq;                                                      \
    app = fmaf(-tt_,papq_,app); aqq = fmaf(tt_,papq_,aqq); apq = 0.0f;      \
    float tp_ = apr, tq_ = aqr;                                             \
    apr = c_*tp_ - s_*tq_; aqr = s_*tp_ + c_*tq_;                           \
    tp_=vp0; tq_=vq0; vp0=c_*tp_-s_*tq_; vq0=s_*tp_+c_*tq_;                 \
    tp_=vp1; tq_=vq1; vp1=c_*tp_-s_*tq_; vq1=s_*tp_+c_*tq_;                 \
    tp_=vp2; tq_=vq2; vp2=c_*tp_-s_*tq_; vq2=s_*tp_+c_*tq_;                 \
  } while(0)

#define CSWAP3F(la,lb, a0,a1,a2, b0,b1,b2) do {                             \
    if (la < lb) { float t_;                                                \
      t_=la; la=lb; lb=t_; t_=a0; a0=b0; b0=t_;                             \
      t_=a1; a1=b1; b1=t_; t_=a2; a2=b2; b2=t_; }                           \
  } while(0)

// ---- redundant small update for iteration `itprev` from acc -> sX/sQ/sR/sT.
// Runs identically in every block. Contains one internal __syncthreads;
// caller must __syncthreads() after before reading other threads' sX/sQ.
// 5 Jacobi sweeps (3x3 cyclic Jacobi is at fp32 round-off by sweep ~4).
template<int ITPREV>
__device__ __forceinline__ void small_update(const float* __restrict__ acc,
                                             const float* __restrict__ X0,
                                             int tid,
                                             float (*sX)[3], float* sQ,
                                             float (*sR)[9], float (*sT)[3],
                                             float* sTn) {
  const int k = tid;
  float lk[Mv], w0v[Mv], w1v[Mv], w2v[Mv], hk[Mv];
  #pragma unroll
  for (int mm=0;mm<Mv;mm++) {
    lk[mm]  = acc[AC_L + mm*Kv + k];
    w0v[mm] = acc[AC_W + (mm*3+0)*Kv + k];
    w1v[mm] = acc[AC_W + (mm*3+1)*Kv + k];
    w2v[mm] = acc[AC_W + (mm*3+2)*Kv + k];
    hk[mm]  = acc[AC_H + mm*Kv + k];
  }
  float xp0 = 0.f, xp1 = 0.f, xp2 = 0.f;
  if (ITPREV <= 1) {
    xp0 = X0[k*3+0]; xp1 = X0[k*3+1]; xp2 = X0[k*3+2];
  }

  if (tid < Mv) {
    int mm = tid;
    const float* st = acc + AC_STATS + mm*16;
    float s0=st[0], s1=st[1], s2v=st[2], s3=st[3], s4=st[4], s5=st[5],
          s6=st[6], s7=st[7], s8=st[8], s9=st[9], s10=st[10], s11=st[11],
          s12=st[12], s13=st[13], s14=st[14], s15=st[15];
    float z = s0;
    float mX0 = s1, mX1 = s2v, mX2 = s3;
    float mW0 = s4, mW1 = s5, mW2 = s6;
    float iz = __builtin_amdgcn_rcpf(z);
    float P00 = s7  - mX0*mW0*iz;
    float P01 = s8  - mX0*mW1*iz;
    float P02 = s9  - mX0*mW2*iz;
    float P10 = s10 - mX1*mW0*iz;
    float P11 = s11 - mX1*mW1*iz;
    float P12 = s12 - mX1*mW2*iz;
    float P20 = s13 - mX2*mW0*iz;
    float P21 = s14 - mX2*mW1*iz;
    float P22 = s15 - mX2*mW2*iz;
    float a00 = P00*P00 + P10*P10 + P20*P20;
    float a01 = P00*P01 + P10*P11 + P20*P21;
    float a02 = P00*P02 + P10*P12 + P20*P22;
    float a11 = P01*P01 + P11*P11 + P21*P21;
    float a12 = P01*P02 + P11*P12 + P21*P22;
    float a22 = P02*P02 + P12*P12 + P22*P22;
    float v00=1, v01=0, v02=0, v10=0, v11=1, v12=0, v20=0, v21=0, v22=1;
    #pragma unroll 1
    for (int sweep = 0; sweep < 5; sweep++) {
      JROTF(a00,a11,a01, a02,a12, v00,v10,v20, v01,v11,v21);
      JROTF(a00,a22,a02, a01,a12, v00,v10,v20, v02,v12,v22);
      JROTF(a11,a22,a12, a01,a02, v01,v11,v21, v02,v12,v22);
    }
    float l0 = a00, l1 = a11, l2 = a22;
    CSWAP3F(l0,l1, v00,v10,v20, v01,v11,v21);
    CSWAP3F(l1,l2, v01,v11,v21, v02,v12,v22);
    CSWAP3F(l0,l1, v00,v10,v20, v01,v11,v21);
    float detP = P00*(P11*P22-P12*P21) - P01*(P10*P22-P12*P20)
               + P02*(P10*P21-P11*P20);
    float s2d = (detP < 0.0f) ? -1.0f : 1.0f;
    float tiny = 1e-18f*l0 + 1e-30f;
    float w0i = __builtin_amdgcn_rsqf(fmaxf(l0,tiny));
    float w1i = __builtin_amdgcn_rsqf(fmaxf(l1,tiny));
    float w2i = s2d*__builtin_amdgcn_rsqf(fmaxf(l2,tiny));
    float M00 = w0i*v00*v00 + w1i*v01*v01 + w2i*v02*v02;
    float M01 = w0i*v00*v10 + w1i*v01*v11 + w2i*v02*v12;
    float M02 = w0i*v00*v20 + w1i*v01*v21 + w2i*v02*v22;
    float M11 = w0i*v10*v10 + w1i*v11*v11 + w2i*v12*v12;
    float M12 = w0i*v10*v20 + w1i*v11*v21 + w2i*v12*v22;
    float M22 = w0i*v20*v20 + w1i*v21*v21 + w2i*v22*v22;
    float R00n = P00*M00 + P01*M01 + P02*M02;
    float R01n = P00*M01 + P01*M11 + P02*M12;
    float R02n = P00*M02 + P01*M12 + P02*M22;
    float R10n = P10*M00 + P11*M01 + P12*M02;
    float R11n = P10*M01 + P11*M11 + P12*M12;
    float R12n = P10*M02 + P11*M12 + P12*M22;
    float R20n = P20*M00 + P21*M01 + P22*M02;
    float R21n = P20*M01 + P21*M11 + P22*M12;
    float R22n = P20*M02 + P21*M12 + P22*M22;
    float tm0 = (mX0 - (R00n*mW0 + R01n*mW1 + R02n*mW2))*iz;
    float tm1 = (mX1 - (R10n*mW0 + R11n*mW1 + R12n*mW2))*iz;
    float tm2 = (mX2 - (R20n*mW0 + R21n*mW1 + R22n*mW2))*iz;
    sR[mm][0]=R00n; sR[mm][1]=R01n; sR[mm][2]=R02n;
    sR[mm][3]=R10n; sR[mm][4]=R11n; sR[mm][5]=R12n;
    sR[mm][6]=R20n; sR[mm][7]=R21n; sR[mm][8]=R22n;
    sT[mm][0]=tm0; sT[mm][1]=tm1; sT[mm][2]=tm2;
    sTn[mm] = tm0*tm0 + tm1*tm1 + tm2*tm2;
  }
  __syncthreads();
  {
    float den = 0.f, Xn0=0.f, Xn1=0.f, Xn2=0.f, S2=0.f;
    #pragma unroll
    for (int mm=0;mm<Mv;mm++) {
      float r0 = sR[mm][0]*w0v[mm] + sR[mm][1]*w1v[mm] + sR[mm][2]*w2v[mm];
      float r1 = sR[mm][3]*w0v[mm] + sR[mm][4]*w1v[mm] + sR[mm][5]*w2v[mm];
      float r2 = sR[mm][6]*w0v[mm] + sR[mm][7]*w1v[mm] + sR[mm][8]*w2v[mm];
      float tt0 = sT[mm][0], tt1 = sT[mm][1], tt2 = sT[mm][2];
      den += lk[mm];
      Xn0 += r0 + tt0*lk[mm]; Xn1 += r1 + tt1*lk[mm]; Xn2 += r2 + tt2*lk[mm];
      S2  += hk[mm] + 2.f*(tt0*r0+tt1*r1+tt2*r2) + sTn[mm]*lk[mm];
    }
    float x0, x1, x2;
    if (ITPREV > 1) { float inv = __builtin_amdgcn_rcpf(den);
                      x0=Xn0*inv; x1=Xn1*inv; x2=Xn2*inv; }
    else            { x0=xp0; x1=xp1; x2=xp2; }
    float wn = S2 + (x0*x0+x1*x1+x2*x2)*den - 2.f*(x0*Xn0+x1*Xn1+x2*Xn2);
    float qn = 3.f*den / (wn + 3.f*den*EPSILON_C);
    sX[k][0]=x0; sX[k][1]=x1; sX[k][2]=x2;
    sQ[k] = qn;
  }
}

// ------------------------------------------- one-iteration kernel (512 blocks)
// Register-tiled two-pass (R9 structure, best verified: 175.4 us total).
template<int IT>
__global__ __launch_bounds__(256) void p_iter(const float* __restrict__ Vs,
                                              const float* __restrict__ X0,
                                              const float* __restrict__ Q0,
                                              float* __restrict__ ws) {
  __shared__ __align__(16) float sC4[Kv][4];   // {kXx,kXy,kXz,kA} swizzled
  __shared__ float sKC[Kv];                    // kQ32*2^kB swizzled
  __shared__ __align__(16) float sP4[NPB][4];  // {px,py,pz,tvn} swizzled
  __shared__ __align__(16) float sV4[NPB][4];  // {vx,vy,vz,vn} swizzled
  __shared__ float sLi[NPB];                   // -log2(S+beta) swizzled
  __shared__ float st4[4][16];
  __shared__ float sX[Kv][3];
  __shared__ float sQ[Kv];
  __shared__ float sR[Mv][9];
  __shared__ float sT[Mv][3];
  __shared__ float sTn[Mv];
  __shared__ float sredq[4];
  __shared__ float sredt[12];

  int tid  = threadIdx.x;
  int wave = tid >> 6, lane = tid & 63;
  int bid  = blockIdx.x;
  int m    = bid / BPM;
  int blk  = bid % BPM;
  int n0   = blk * NPB;

  float* acc  = ws + (IT % 3)*ACCSZ;
  float* accz = ws + ((IT+1) % 3)*ACCSZ;

  // ---- hoisted loads: own point + own q (latency hides under the prologue)
  const float* V0 = Vs + (size_t)(m*3+0)*Nv;
  const float* V1 = Vs + (size_t)(m*3+1)*Nv;
  const float* V2 = Vs + (size_t)(m*3+2)*Nv;
  float vx=0.f, vy=0.f, vz=0.f;
  if (tid < NPB) {
    int n = n0 + tid;
    vx = V0[n]; vy = V1[n]; vz = V2[n];
  }
  float q_own = Q0[tid];
  { float s = wave_red_sum(q_own);
    if (lane == 0) sredq[wave] = s; }

  float t00=0.f, t01=0.f, t02=0.f;
  if (IT == 0) {
    // t0 (redundant per block: mean over ALL Nv points of own m; L2-resident)
    float sx=0.f, sy=0.f, sz=0.f;
    for (int n = tid; n < Nv; n += 256) { sx += V0[n]; sy += V1[n]; sz += V2[n]; }
    sx = wave_red_sum(sx); sy = wave_red_sum(sy); sz = wave_red_sum(sz);
    if (lane == 0) { sredt[wave] = sx; sredt[4+wave] = sy; sredt[8+wave] = sz; }
    sX[tid][0] = X0[3*tid+0];
    sX[tid][1] = X0[3*tid+1];
    sX[tid][2] = X0[3*tid+2];
    sQ[tid]    = q_own;
    __syncthreads();
    t00 = -(sredt[0]+sredt[1]+sredt[2]+sredt[3]) * (1.f/(float)Nv);
    t01 = -(sredt[4]+sredt[5]+sredt[6]+sredt[7]) * (1.f/(float)Nv);
    t02 = -(sredt[8]+sredt[9]+sredt[10]+sredt[11]) * (1.f/(float)Nv);
  } else {
    const float* accp = ws + ((IT+2) % 3)*ACCSZ;  // (IT-1)%3
    small_update<(IT > 0) ? (IT-1) : 0>(accp, X0, tid, sX, sQ, sR, sT, sTn);
    __syncthreads();
  }
  float beta;
  { float mq = (sredq[0]+sredq[1]+sredq[2]+sredq[3]) * (1.f/(float)Kv);
    beta = GAMMA_C * mq * sqrtf(mq); }

  // partitioned zero of buffer (IT+1)%3 (21*512 >= ACCSZ)
  if (IT < NITER-1) {
    int base = bid*21;
    if (tid < 21 && base + tid < ACCSZ) accz[base + tid] = 0.f;
  }

  // own-m R, t
  float R00,R01,R02,R10,R11,R12,R20,R21,R22, t0,t1,t2;
  if (IT == 0) {
    R00=1;R01=0;R02=0; R10=0;R11=1;R12=0; R20=0;R21=0;R22=1;
    t0=t00; t1=t01; t2=t02;
  } else {
    R00=sR[m][0];R01=sR[m][1];R02=sR[m][2];
    R10=sR[m][3];R11=sR[m][4];R12=sR[m][5];
    R20=sR[m][6];R21=sR[m][7];R22=sR[m][8];
    t0=sT[m][0]; t1=sT[m][1]; t2=sT[m][2];
  }

  // ---- prep: per-k coefficients (k=tid) -> swizzled LDS
  const float L2E = 1.4426950408889634f;
  {
    float xx = sX[tid][0], xy = sX[tid][1], xz = sX[tid][2];
    float q  = sQ[tid];
    float qL = q * L2E;
    float kA = -0.5f*qL;
    float kB = kA*(xx*xx+xy*xy+xz*xz);
    float kQ32 = q*sqrtf(q);
    int rr = SWZK(tid);
    *reinterpret_cast<float4*>(&sC4[rr][0]) = make_float4(qL*xx, qL*xy, qL*xz, kA);
    sKC[rr] = kQ32 * __builtin_amdgcn_exp2f(kB);
  }
  // ---- transform own point (loads already in flight/registers)
  if (tid < NPB) {
    float px = fmaf(R00,vx, fmaf(R01,vy, fmaf(R02,vz, t0)));
    float py = fmaf(R10,vx, fmaf(R11,vy, fmaf(R12,vz, t1)));
    float pz = fmaf(R20,vx, fmaf(R21,vy, fmaf(R22,vz, t2)));
    float tvn = fmaf(px,px, fmaf(py,py, pz*pz));
    float vn  = fmaf(vx,vx, fmaf(vy,vy, vz*vz));
    int pr = SWZP(tid);
    *reinterpret_cast<float4*>(&sP4[pr][0]) = make_float4(px,py,pz,tvn);
    *reinterpret_cast<float4*>(&sV4[pr][0]) = make_float4(vx,vy,vz,vn);
  }
  __syncthreads();

  // ---- pass 1: denominators. thread (pg = tid>>2, ks = tid&3)
  {
    int ks = tid & 3, pg = tid >> 2;          // pg in 0..63, points 2pg, 2pg+1
    float4 P0 = *reinterpret_cast<const float4*>(&sP4[SWZP(2*pg+0)][0]);
    float4 P1 = *reinterpret_cast<const float4*>(&sP4[SWZP(2*pg+1)][0]);
    float s0 = 0.f, s1 = 0.f;
    #pragma unroll 4
    for (int j = 0; j < Kv/4; j++) {          // k = ks*64 + j
      int row = (j<<2) | ks;
      float4 c4 = *reinterpret_cast<const float4*>(&sC4[row][0]);
      float kc = sKC[row];
      float a0 = fmaf(P0.x,c4.x, fmaf(P0.y,c4.y, fmaf(P0.z,c4.z, P0.w*c4.w)));
      float a1 = fmaf(P1.x,c4.x, fmaf(P1.y,c4.y, fmaf(P1.z,c4.z, P1.w*c4.w)));
      s0 = fmaf(__builtin_amdgcn_exp2f(a0), kc, s0);
      s1 = fmaf(__builtin_amdgcn_exp2f(a1), kc, s1);
    }
    float S0 = quad_red_sum(s0);
    float S1 = quad_red_sum(s1);
    if (ks < 2) {
      float Ssel = (ks == 1) ? S1 : S0;
      sLi[SWZP(2*pg + ks)] = -__log2f(Ssel + beta);
    }
  }
  __syncthreads();

  // ---- pass 2: thread (kg = tid>>2, ns = tid&3); owns k = 4kg..4kg+3
  float cXx0,cXy0,cXz0,cA0,cC0, cXx1,cXy1,cXz1,cA1,cC1,
        cXx2,cXy2,cXz2,cA2,cC2, cXx3,cXy3,cXz3,cA3,cC3;
  {
    int kg = tid >> 2;
    #define LDC(c) { int rr = SWZK(4*kg + c); \
      float4 t4 = *reinterpret_cast<const float4*>(&sC4[rr][0]); \
      cXx##c=t4.x; cXy##c=t4.y; cXz##c=t4.z; cA##c=t4.w; cC##c=sKC[rr]; }
    LDC(0) LDC(1) LDC(2) LDC(3)
    #undef LDC
  }
  float L0=0,L1=0,L2=0,L3=0, Wx0=0,Wx1=0,Wx2=0,Wx3=0,
        Wy0=0,Wy1=0,Wy2=0,Wy3=0, Wz0=0,Wz1=0,Wz2=0,Wz3=0,
        H0=0,H1=0,H2=0,H3=0;
  {
    int ns = tid & 3;
    #pragma unroll 4
    for (int j = 0; j < NPB/4; j++) {         // n = ns*32 + j
      int prow = (j<<2) | ns;
      float4 p4 = *reinterpret_cast<const float4*>(&sP4[prow][0]);
      float4 v4 = *reinterpret_cast<const float4*>(&sV4[prow][0]);
      float li = sLi[prow];
      #define P2K(c) { \
        float arg = fmaf(p4.w, cA##c, li); \
        arg = fmaf(p4.x, cXx##c, fmaf(p4.y, cXy##c, fmaf(p4.z, cXz##c, arg))); \
        float e = __builtin_amdgcn_exp2f(arg) * cC##c; \
        L##c += e; \
        Wx##c = fmaf(e, v4.x, Wx##c); Wy##c = fmaf(e, v4.y, Wy##c); \
        Wz##c = fmaf(e, v4.z, Wz##c); H##c  = fmaf(e, v4.w, H##c); }
      P2K(0) P2K(1) P2K(2) P2K(3)
      #undef P2K
    }
  }
  // quad-reduce the 4 n-quarters; then thread t owns k = t
  L0=quad_red_sum(L0); L1=quad_red_sum(L1); L2=quad_red_sum(L2); L3=quad_red_sum(L3);
  Wx0=quad_red_sum(Wx0); Wx1=quad_red_sum(Wx1); Wx2=quad_red_sum(Wx2); Wx3=quad_red_sum(Wx3);
  Wy0=quad_red_sum(Wy0); Wy1=quad_red_sum(Wy1); Wy2=quad_red_sum(Wy2); Wy3=quad_red_sum(Wy3);
  Wz0=quad_red_sum(Wz0); Wz1=quad_red_sum(Wz1); Wz2=quad_red_sum(Wz2); Wz3=quad_red_sum(Wz3);
  H0=quad_red_sum(H0); H1=quad_red_sum(H1); H2=quad_red_sum(H2); H3=quad_red_sum(H3);
  int c = tid & 3;
  float vL  = sel4(c, L0,L1,L2,L3);
  float vWx = sel4(c, Wx0,Wx1,Wx2,Wx3);
  float vWy = sel4(c, Wy0,Wy1,Wy2,Wy3);
  float vWz = sel4(c, Wz0,Wz1,Wz2,Wz3);
  float vH  = sel4(c, H0,H1,H2,H3);
  atomicAdd(&acc[AC_L + m*Kv + tid], vL);
  atomicAdd(&acc[AC_W + (m*3+0)*Kv + tid], vWx);
  atomicAdd(&acc[AC_W + (m*3+1)*Kv + tid], vWy);
  atomicAdd(&acc[AC_W + (m*3+2)*Kv + tid], vWz);
  atomicAdd(&acc[AC_H + m*Kv + tid], vH);

  // ---- stats epilogue (k = tid)
  {
    float q  = sQ[tid];
    float x0 = sX[tid][0], x1 = sX[tid][1], x2 = sX[tid][2];
    float bk = vL*q;
    float sw0 = vWx*q, sw1 = vWy*q, sw2 = vWz*q;
    float pr[16];
    pr[0]=bk;  pr[1]=bk*x0; pr[2]=bk*x1; pr[3]=bk*x2;
    pr[4]=sw0; pr[5]=sw1;   pr[6]=sw2;
    pr[7]=sw0*x0;  pr[8]=sw1*x0;  pr[9]=sw2*x0;
    pr[10]=sw0*x1; pr[11]=sw1*x1; pr[12]=sw2*x1;
    pr[13]=sw0*x2; pr[14]=sw1*x2; pr[15]=sw2*x2;
    float red[16];
    #pragma unroll
    for (int v2=0; v2<16; v2++) red[v2] = wave_red_sum(pr[v2]);
    if (lane == 0) {
      #pragma unroll
      for (int v2=0; v2<16; v2++) st4[wave][v2] = red[v2];
    }
    __syncthreads();
    if (tid < 16)
      atomicAdd(&acc[AC_STATS + m*16 + ((tid + blk) & 15)],
                st4[0][(tid+blk)&15]+st4[1][(tid+blk)&15]+
                st4[2][(tid+blk)&15]+st4[3][(tid+blk)&15]);
  }
}

// ------------------------------- final: prologue finalizes iter 5, then write
#define OUT_TOTAL (Mv*3*Nv + 72 + 24 + Kv*3)
__global__ __launch_bounds__(256) void p3_final(const float* __restrict__ Vs,
                                                const float* __restrict__ X0,
                                                const float* __restrict__ ws,
                                                float* __restrict__ out) {
  __shared__ float sX[Kv][3];
  __shared__ float sQ[Kv];
  __shared__ float sR[Mv][9];
  __shared__ float sT[Mv][3];
  __shared__ float sTn[Mv];
  int tid = threadIdx.x;
  const float* acc = ws + ((NITER-1) % 3)*ACCSZ;
  small_update<NITER-1>(acc, X0, tid, sX, sQ, sR, sT, sTn);
  __syncthreads();

  for (int idx = blockIdx.x*256 + tid; idx < OUT_TOTAL; idx += 256*256) {
    if (idx < Mv*3*Nv) {
      int m = idx / (3*Nv);
      int r = idx % (3*Nv);
      int d = r / Nv;
      int n = r % Nv;
      float vx = Vs[(size_t)(m*3+0)*Nv + n];
      float vy = Vs[(size_t)(m*3+1)*Nv + n];
      float vz = Vs[(size_t)(m*3+2)*Nv + n];
      out[idx] = fmaf(sR[m][d*3+0],vx,
                 fmaf(sR[m][d*3+1],vy,
                 fmaf(sR[m][d*3+2],vz, sT[m][d])));
    } else {
      int j = idx - Mv*3*Nv;
      float v;
      if (j < 72)      v = ((float*)sR)[j];
      else if (j < 96) v = ((float*)sT)[j-72];
      else             v = ((float*)sX)[j-96];
      out[idx] = v;
    }
  }
}

extern "C" void kernel_launch(void* const* d_in, const int* in_sizes, int n_in,
                              void* d_out, int out_size, void* d_ws, size_t ws_size,
                              hipStream_t stream) {
  const float* Vs = (const float*)d_in[0];
  const float* X0 = (const float*)d_in[1];
  const float* Q0 = (const float*)d_in[2];
  float* out = (float*)d_out;
  float* ws  = (float*)d_ws;

  // zero acc buffer 0 (buffers 1,2 are zeroed inside p_iter<0>/<1>)
  hipMemsetAsync(ws, 0, ACCSZ * sizeof(float), stream);
  p_iter<0><<<NBLK, 256, 0, stream>>>(Vs, X0, Q0, ws);
  p_iter<1><<<NBLK, 256, 0, stream>>>(Vs, X0, Q0, ws);
  p_iter<2><<<NBLK, 256, 0, stream>>>(Vs, X0, Q0, ws);
  p_iter<3><<<NBLK, 256, 0, stream>>>(Vs, X0, Q0, ws);
  p_iter<4><<<NBLK, 256, 0, stream>>>(Vs, X0, Q0, ws);
  p_iter<5><<<NBLK, 256, 0, stream>>>(Vs, X0, Q0, ws);
  p3_final<<<256, 256, 0, stream>>>(Vs, X0, ws, out);
}